// Round 11
// baseline (149.291 us; speedup 1.0000x reference)
//
#include <hip/hip_runtime.h>

#define LOG2E 1.4426950408889634f

// Problem constants
constexpr int Bb = 4, LQ = 512, LK = 512, QS = 512, H = 256, DV = 512;
constexpr int M = 2048;   // B*LQ

// Workspace byte offsets
constexpr size_t OFF_EQT = 0;            // [256][2048] f32 (2 MiB) exp2-domain q proj
constexpr size_t OFF_EKT = 2u << 20;     // [256][2048] f32 (2 MiB)
constexpr size_t OFF_PQ  = 4u << 20;     // [4][512][512] bf16 (2 MiB) P numerators
constexpr size_t OFF_ROW = 6u << 20;     // [8][2048] f32 rowsum partials

using bf16x8 = __attribute__((ext_vector_type(8))) short;
using f32x4v = __attribute__((ext_vector_type(4))) float;

__device__ inline unsigned short f2bf(float x) {
    unsigned int u = __float_as_uint(x);
    u += 0x7FFFu + ((u >> 16) & 1u);      // round-to-nearest-even
    return (unsigned short)(u >> 16);
}
__device__ inline unsigned int pk2(float lo, float hi) {
    return (unsigned int)f2bf(lo) | ((unsigned int)f2bf(hi) << 16);
}

// ---------------------------------------------------------------------------
// Kernel A: proj via bf16 MFMA + exp2 epilogue, transposed fp32 output.
//   EqT[n][m] = exp2( clamp( scale*(A[m]·W[n] + bias[n]), ±30 ) )
// (unchanged from R9/R10 — measured fast)
// ---------------------------------------------------------------------------
__global__ __launch_bounds__(256) void proj_mfma(
    const float* __restrict__ query, const float* __restrict__ key,
    const float* __restrict__ wq, const float* __restrict__ wk,
    const float* __restrict__ bq, const float* __restrict__ bk,
    char* __restrict__ ws, float scale)
{
    const int z = blockIdx.z;
    const float* A    = z ? key : query;   // [2048][512]
    const float* W    = z ? wk : wq;       // [256][512]
    const float* bias = z ? bk : bq;
    float* out = (float*)(ws + (z ? OFF_EKT : OFF_EQT));   // [256][2048]

    __shared__ unsigned short Als[64][136];
    __shared__ unsigned short Wls[64][136];
    __shared__ float Ot[64][68];

    const int mb = blockIdx.x * 64, nb = blockIdx.y * 64;
    const int tid = threadIdx.x;
    const int wid = tid >> 6, lane = tid & 63;
    const int ml = lane & 15, quad = lane >> 4;

    f32x4v acc[4] = {{0,0,0,0},{0,0,0,0},{0,0,0,0},{0,0,0,0}};

    for (int kc = 0; kc < QS; kc += 128) {
        __syncthreads();
#pragma unroll
        for (int it = 0; it < 4; ++it) {
            int u = tid + it * 256;          // 0..1023 units of 8 elems
            int row = u >> 4, c8 = (u & 15) * 8;
            float4 a0 = *(const float4*)(A + (size_t)(mb + row) * 512 + kc + c8);
            float4 a1 = *(const float4*)(A + (size_t)(mb + row) * 512 + kc + c8 + 4);
            uint4 pa = { pk2(a0.x, a0.y), pk2(a0.z, a0.w), pk2(a1.x, a1.y), pk2(a1.z, a1.w) };
            *(uint4*)&Als[row][c8] = pa;
            float4 w0 = *(const float4*)(W + (size_t)(nb + row) * 512 + kc + c8);
            float4 w1 = *(const float4*)(W + (size_t)(nb + row) * 512 + kc + c8 + 4);
            uint4 pw = { pk2(w0.x, w0.y), pk2(w0.z, w0.w), pk2(w1.x, w1.y), pk2(w1.z, w1.w) };
            *(uint4*)&Wls[row][c8] = pw;
        }
        __syncthreads();
#pragma unroll
        for (int s = 0; s < 4; ++s) {
            int k = s * 32 + quad * 8;
            bf16x8 af = *(const bf16x8*)&Als[wid * 16 + ml][k];
#pragma unroll
            for (int nt = 0; nt < 4; ++nt) {
                bf16x8 bfr = *(const bf16x8*)&Wls[nt * 16 + ml][k];
                acc[nt] = __builtin_amdgcn_mfma_f32_16x16x32_bf16(af, bfr, acc[nt], 0, 0, 0);
            }
        }
    }
    __syncthreads();
#pragma unroll
    for (int nt = 0; nt < 4; ++nt)
#pragma unroll
        for (int r = 0; r < 4; ++r)
            Ot[nt * 16 + ml][wid * 16 + quad * 4 + r] = acc[nt][r];
    __syncthreads();
    {
        int r0 = tid >> 2;            // n-local 0..63
        int c0 = (tid & 3) * 16;      // m-local base
        float bs = bias[nb + r0];
#pragma unroll
        for (int g = 0; g < 4; ++g) {
            float4 v = *(const float4*)&Ot[r0][c0 + g * 4];
            float4 o;
            o.x = __builtin_amdgcn_exp2f(fminf(fmaxf(scale * (v.x + bs), -30.f), 30.f));
            o.y = __builtin_amdgcn_exp2f(fminf(fmaxf(scale * (v.y + bs), -30.f), 30.f));
            o.z = __builtin_amdgcn_exp2f(fminf(fmaxf(scale * (v.z + bs), -30.f), 30.f));
            o.w = __builtin_amdgcn_exp2f(fminf(fmaxf(scale * (v.w + bs), -30.f), 30.f));
            *(float4*)(out + (size_t)(nb + r0) * 2048 + mb + c0 + g * 4) = o;
        }
    }
}

// ---------------------------------------------------------------------------
// Kernel B: scores -> P = exp2(-acc) bf16 [b][q][k] + per-ktile row partials.
//   acc(q,k) = sum_h Wv2[h]/(1 + Eq[h][q]*Ek[h][k]),  h-terms paired
//   (one rcp per two h).
// R11 change: SOFTWARE-PIPELINED inner loop — iteration hh+2's four LDS
// fragments are loaded into rotation registers BEFORE hh's 96-instr compute
// block (~192 cyc of cover > ~120-cyc ds_read latency), plus cross-chunk
// global register prefetch.  256 thr, 64x64 tile, 4x4/thread (the config
// where LDS-pipe and VALU-issue floors balance at ~10 µs each).
// Grid (8,8,4) = 256 blocks.
// ---------------------------------------------------------------------------
__global__ __launch_bounds__(256) void score_kernel(
    const float* __restrict__ wvp, char* __restrict__ ws)
{
    const float* EqT = (const float*)(ws + OFF_EQT);   // [256][2048]
    const float* EkT = (const float*)(ws + OFF_EKT);
    unsigned short* Pq = (unsigned short*)(ws + OFF_PQ);  // [4][512][512] bf16
    float* rowpart = (float*)(ws + OFF_ROW);              // [8][2048]

    __shared__ float Qs[64][64];
    __shared__ float Ks[64][64];
    __shared__ float Wv2[H];
    __shared__ float redS[4][64];

    const int b  = blockIdx.z;
    const int qb = blockIdx.x * 64;
    const int kt = blockIdx.y;
    const int kb = kt * 64;
    const int tid = threadIdx.x;
    const int tx = tid & 15;       // q frag: tx*4 + i
    const int ty = tid >> 4;       // k frag: ty*4 + j   (0..15)
    const int w  = tid >> 6;
    const int lane = tid & 63;

    Wv2[tid] = wvp[tid] * (2.0f * LOG2E);   // blockDim == H == 256

    const int mq = b * LQ + qb;
    const int mk = b * LK + kb;
    const int sh = tid >> 4;       // staging row 0..15 (+16 steps)
    const int sm = (tid & 15) * 4;

    float4 pq[4], pk[4];
#pragma unroll
    for (int it = 0; it < 4; ++it) {
        pq[it] = *(const float4*)(EqT + (size_t)(sh + 16 * it) * M + mq + sm);
        pk[it] = *(const float4*)(EkT + (size_t)(sh + 16 * it) * M + mk + sm);
    }

    float acc[4][4] = {};

    for (int h0 = 0; h0 < H; h0 += 64) {
        __syncthreads();   // also covers the Wv2 write on the first pass
#pragma unroll
        for (int it = 0; it < 4; ++it) {
            *(float4*)&Qs[sh + 16 * it][sm] = pq[it];
            *(float4*)&Ks[sh + 16 * it][sm] = pk[it];
        }
        __syncthreads();
        if (h0 + 64 < H) {
#pragma unroll
            for (int it = 0; it < 4; ++it) {
                pq[it] = *(const float4*)(EqT + (size_t)(h0 + 64 + sh + 16 * it) * M + mq + sm);
                pk[it] = *(const float4*)(EkT + (size_t)(h0 + 64 + sh + 16 * it) * M + mk + sm);
            }
        }
        // -------- software-pipelined compute over 32 hh-pairs --------
        float4 q1 = *(const float4*)&Qs[0][tx * 4];
        float4 q2 = *(const float4*)&Qs[1][tx * 4];
        float4 k1 = *(const float4*)&Ks[0][ty * 4];
        float4 k2 = *(const float4*)&Ks[1][ty * 4];
#pragma unroll 4
        for (int hh = 0; hh < 64; hh += 2) {
            const int hn = (hh + 2) & 63;   // wrap: last iter reloads row 0 (harmless)
            float4 q1n = *(const float4*)&Qs[hn][tx * 4];
            float4 q2n = *(const float4*)&Qs[hn + 1][tx * 4];
            float4 k1n = *(const float4*)&Ks[hn][ty * 4];
            float4 k2n = *(const float4*)&Ks[hn + 1][ty * 4];
            const float w1 = Wv2[h0 + hh];
            const float w2 = Wv2[h0 + hh + 1];
            const float q1a[4] = {q1.x, q1.y, q1.z, q1.w};
            const float q2a[4] = {q2.x, q2.y, q2.z, q2.w};
            const float k1a[4] = {k1.x, k1.y, k1.z, k1.w};
            const float k2a[4] = {k2.x, k2.y, k2.z, k2.w};
#pragma unroll
            for (int i = 0; i < 4; ++i)
#pragma unroll
                for (int j = 0; j < 4; ++j) {
                    float ta = fmaf(q1a[i], k1a[j], 1.0f);
                    float tb = fmaf(q2a[i], k2a[j], 1.0f);
                    float num = fmaf(w1, tb, w2 * ta);
                    acc[i][j] = fmaf(num, __builtin_amdgcn_rcpf(ta * tb), acc[i][j]);
                }
            q1 = q1n; q2 = q2n; k1 = k1n; k2 = k2n;
        }
    }

    // Epilogue: P = exp2(-acc) -> bf16 Pq[b][q][kb+ty*4..+3]; row partials.
    float ps[4];
#pragma unroll
    for (int i = 0; i < 4; ++i) {
        int q = qb + tx * 4 + i;
        float p0 = __builtin_amdgcn_exp2f(-acc[i][0]);
        float p1 = __builtin_amdgcn_exp2f(-acc[i][1]);
        float p2 = __builtin_amdgcn_exp2f(-acc[i][2]);
        float p3 = __builtin_amdgcn_exp2f(-acc[i][3]);
        ps[i] = (p0 + p1) + (p2 + p3);
        uint2 o = { pk2(p0, p1), pk2(p2, p3) };
        *(uint2*)(Pq + ((size_t)(b * 512 + q) * 512 + kb + ty * 4)) = o;
    }
#pragma unroll
    for (int i = 0; i < 4; ++i) {
        ps[i] += __shfl_xor(ps[i], 16, 64);
        ps[i] += __shfl_xor(ps[i], 32, 64);
    }
    if (lane < 16) {
#pragma unroll
        for (int i = 0; i < 4; ++i) redS[w][tx * 4 + i] = ps[i];
    }
    __syncthreads();
    if (tid < 64) {
        float s = (redS[0][tid] + redS[1][tid]) + (redS[2][tid] + redS[3][tid]);
        rowpart[(size_t)kt * 2048 + b * 512 + qb + tid] = s;
    }
}

// ---------------------------------------------------------------------------
// Kernel C: out = (P @ V) / rowsum via bf16 MFMA.  (unchanged from R9/R10)
// ---------------------------------------------------------------------------
__global__ __launch_bounds__(256) void av_mfma(
    const float* __restrict__ V, const char* __restrict__ wsc,
    float* __restrict__ O)
{
    const unsigned short* Pq = (const unsigned short*)(wsc + OFF_PQ);
    const float* rowpart = (const float*)(wsc + OFF_ROW);

    __shared__ unsigned short Pls[64][136];
    __shared__ unsigned short Vls[64][136];

    const int b = blockIdx.z, qb = blockIdx.x * 64, nb = blockIdx.y * 64;
    const int tid = threadIdx.x;
    const int wid = tid >> 6, lane = tid & 63;
    const int ml = lane & 15, quad = lane >> 4;
    const unsigned short* Pb = Pq + (size_t)b * 512 * 512;
    const float* Vb = V + (size_t)b * 512 * 512;

    f32x4v acc[4] = {{0,0,0,0},{0,0,0,0},{0,0,0,0},{0,0,0,0}};

    for (int kc = 0; kc < LK; kc += 128) {
        __syncthreads();
#pragma unroll
        for (int it = 0; it < 4; ++it) {
            int u = tid + it * 256;
            int row = u >> 4, c8 = (u & 15) * 8;
            *(uint4*)&Pls[row][c8] = *(const uint4*)(Pb + (size_t)(qb + row) * 512 + kc + c8);
        }
#pragma unroll
        for (int it = 0; it < 8; ++it) {
            int u = tid + it * 256;           // 2048 float4 units
            int k = u >> 4, c4 = (u & 15) * 4;
            float4 v4 = *(const float4*)(Vb + (size_t)(kc + k) * 512 + nb + c4);
            Vls[c4 + 0][k] = f2bf(v4.x);
            Vls[c4 + 1][k] = f2bf(v4.y);
            Vls[c4 + 2][k] = f2bf(v4.z);
            Vls[c4 + 3][k] = f2bf(v4.w);
        }
        __syncthreads();
#pragma unroll
        for (int s = 0; s < 4; ++s) {
            int k = s * 32 + quad * 8;
            bf16x8 af = *(const bf16x8*)&Pls[wid * 16 + ml][k];
#pragma unroll
            for (int nt = 0; nt < 4; ++nt) {
                bf16x8 bfr = *(const bf16x8*)&Vls[nt * 16 + ml][k];
                acc[nt] = __builtin_amdgcn_mfma_f32_16x16x32_bf16(af, bfr, acc[nt], 0, 0, 0);
            }
        }
    }

    float rr[4];
#pragma unroll
    for (int r = 0; r < 4; ++r) {
        int q = qb + wid * 16 + quad * 4 + r;
        float rs = 0.f;
#pragma unroll
        for (int t = 0; t < 8; ++t) rs += rowpart[(size_t)t * 2048 + b * 512 + q];
        rr[r] = 1.0f / rs;
    }
#pragma unroll
    for (int nt = 0; nt < 4; ++nt)
#pragma unroll
        for (int r = 0; r < 4; ++r) {
            int q = qb + wid * 16 + quad * 4 + r;
            O[((size_t)b * 512 + q) * 512 + nb + nt * 16 + ml] = acc[nt][r] * rr[r];
        }
}

extern "C" void kernel_launch(void* const* d_in, const int* in_sizes, int n_in,
                              void* d_out, int out_size, void* d_ws, size_t ws_size,
                              hipStream_t stream) {
    const float* query = (const float*)d_in[0];
    const float* key   = (const float*)d_in[1];
    const float* value = (const float*)d_in[2];
    const float* wq    = (const float*)d_in[3];
    const float* bq    = (const float*)d_in[4];
    const float* wk    = (const float*)d_in[5];
    const float* bk    = (const float*)d_in[6];
    const float* wv    = (const float*)d_in[7];
    // d_in[8] = bv: row-constant -> softmax-invariant, dropped.
    float* out = (float*)d_out;
    char* ws = (char*)d_ws;

    const float c2 = 2.0f * LOG2E;

    proj_mfma<<<dim3(32, 4, 2), 256, 0, stream>>>(query, key, wq, wk, bq, bk, ws, c2);
    score_kernel<<<dim3(8, 8, Bb), 256, 0, stream>>>(wv, ws);
    av_mfma<<<dim3(8, 8, Bb), 256, 0, stream>>>(value, ws, out);
}

// Round 12
// 140.957 us; speedup vs baseline: 1.0591x; 1.0591x over previous
//
#include <hip/hip_runtime.h>

#define LOG2E 1.4426950408889634f

// Problem constants
constexpr int Bb = 4, LQ = 512, LK = 512, QS = 512, H = 256, DV = 512;
constexpr int M = 2048;   // B*LQ

// Workspace byte offsets
constexpr size_t OFF_EQT = 0;            // [256][2048] f32 (2 MiB) exp2-domain q proj
constexpr size_t OFF_EKT = 2u << 20;     // [256][2048] f32 (2 MiB)
constexpr size_t OFF_PQ  = 4u << 20;     // [4][512][512] bf16 (2 MiB) P numerators
constexpr size_t OFF_ROW = 6u << 20;     // [8][2048] f32 rowsum partials

using bf16x8 = __attribute__((ext_vector_type(8))) short;
using f32x4v = __attribute__((ext_vector_type(4))) float;

__device__ inline unsigned short f2bf(float x) {
    unsigned int u = __float_as_uint(x);
    u += 0x7FFFu + ((u >> 16) & 1u);      // round-to-nearest-even
    return (unsigned short)(u >> 16);
}
__device__ inline unsigned int pk2(float lo, float hi) {
    return (unsigned int)f2bf(lo) | ((unsigned int)f2bf(hi) << 16);
}

// ---------------------------------------------------------------------------
// Kernel A: proj via bf16 MFMA + exp2 epilogue, transposed fp32 output.
//   EqT[n][m] = exp2( clamp( scale*(A[m]·W[n] + bias[n]), ±30 ) )
// (unchanged from R9/R10 — measured fast)
// ---------------------------------------------------------------------------
__global__ __launch_bounds__(256) void proj_mfma(
    const float* __restrict__ query, const float* __restrict__ key,
    const float* __restrict__ wq, const float* __restrict__ wk,
    const float* __restrict__ bq, const float* __restrict__ bk,
    char* __restrict__ ws, float scale)
{
    const int z = blockIdx.z;
    const float* A    = z ? key : query;   // [2048][512]
    const float* W    = z ? wk : wq;       // [256][512]
    const float* bias = z ? bk : bq;
    float* out = (float*)(ws + (z ? OFF_EKT : OFF_EQT));   // [256][2048]

    __shared__ unsigned short Als[64][136];
    __shared__ unsigned short Wls[64][136];
    __shared__ float Ot[64][68];

    const int mb = blockIdx.x * 64, nb = blockIdx.y * 64;
    const int tid = threadIdx.x;
    const int wid = tid >> 6, lane = tid & 63;
    const int ml = lane & 15, quad = lane >> 4;

    f32x4v acc[4] = {{0,0,0,0},{0,0,0,0},{0,0,0,0},{0,0,0,0}};

    for (int kc = 0; kc < QS; kc += 128) {
        __syncthreads();
#pragma unroll
        for (int it = 0; it < 4; ++it) {
            int u = tid + it * 256;          // 0..1023 units of 8 elems
            int row = u >> 4, c8 = (u & 15) * 8;
            float4 a0 = *(const float4*)(A + (size_t)(mb + row) * 512 + kc + c8);
            float4 a1 = *(const float4*)(A + (size_t)(mb + row) * 512 + kc + c8 + 4);
            uint4 pa = { pk2(a0.x, a0.y), pk2(a0.z, a0.w), pk2(a1.x, a1.y), pk2(a1.z, a1.w) };
            *(uint4*)&Als[row][c8] = pa;
            float4 w0 = *(const float4*)(W + (size_t)(nb + row) * 512 + kc + c8);
            float4 w1 = *(const float4*)(W + (size_t)(nb + row) * 512 + kc + c8 + 4);
            uint4 pw = { pk2(w0.x, w0.y), pk2(w0.z, w0.w), pk2(w1.x, w1.y), pk2(w1.z, w1.w) };
            *(uint4*)&Wls[row][c8] = pw;
        }
        __syncthreads();
#pragma unroll
        for (int s = 0; s < 4; ++s) {
            int k = s * 32 + quad * 8;
            bf16x8 af = *(const bf16x8*)&Als[wid * 16 + ml][k];
#pragma unroll
            for (int nt = 0; nt < 4; ++nt) {
                bf16x8 bfr = *(const bf16x8*)&Wls[nt * 16 + ml][k];
                acc[nt] = __builtin_amdgcn_mfma_f32_16x16x32_bf16(af, bfr, acc[nt], 0, 0, 0);
            }
        }
    }
    __syncthreads();
#pragma unroll
    for (int nt = 0; nt < 4; ++nt)
#pragma unroll
        for (int r = 0; r < 4; ++r)
            Ot[nt * 16 + ml][wid * 16 + quad * 4 + r] = acc[nt][r];
    __syncthreads();
    {
        int r0 = tid >> 2;            // n-local 0..63
        int c0 = (tid & 3) * 16;      // m-local base
        float bs = bias[nb + r0];
#pragma unroll
        for (int g = 0; g < 4; ++g) {
            float4 v = *(const float4*)&Ot[r0][c0 + g * 4];
            float4 o;
            o.x = __builtin_amdgcn_exp2f(fminf(fmaxf(scale * (v.x + bs), -30.f), 30.f));
            o.y = __builtin_amdgcn_exp2f(fminf(fmaxf(scale * (v.y + bs), -30.f), 30.f));
            o.z = __builtin_amdgcn_exp2f(fminf(fmaxf(scale * (v.z + bs), -30.f), 30.f));
            o.w = __builtin_amdgcn_exp2f(fminf(fmaxf(scale * (v.w + bs), -30.f), 30.f));
            *(float4*)(out + (size_t)(nb + r0) * 2048 + mb + c0 + g * 4) = o;
        }
    }
}

// ---------------------------------------------------------------------------
// Kernel B: scores -> P = exp2(-acc) bf16 [b][q][k] + per-ktile row partials.
//   acc(q,k) = sum_h Wv2[h]/(1 + Eq[h][q]*Ek[h][k]),  h-terms paired
//   (one rcp per two h — rcp is the quarter-rate trans pipe).
// R12: back to the R9 4x4/256-thr shape (lowest LDS bytes/elem), NO manual
// pipelining (R11's rotation registers regressed — compiler schedules
// better).  Aids: unroll-8 pair loop (wide scheduling window for ds_read
// hoisting) and float2 Wv2 pair loads.  Grid (8,8,4) = 256 blocks.
// ---------------------------------------------------------------------------
__global__ __launch_bounds__(256) void score_kernel(
    const float* __restrict__ wvp, char* __restrict__ ws)
{
    const float* EqT = (const float*)(ws + OFF_EQT);   // [256][2048]
    const float* EkT = (const float*)(ws + OFF_EKT);
    unsigned short* Pq = (unsigned short*)(ws + OFF_PQ);  // [4][512][512] bf16
    float* rowpart = (float*)(ws + OFF_ROW);              // [8][2048]

    __shared__ float Qs[64][64];
    __shared__ float Ks[64][64];
    __shared__ float Wv2[H];
    __shared__ float redS[4][64];

    const int b  = blockIdx.z;
    const int qb = blockIdx.x * 64;
    const int kt = blockIdx.y;
    const int kb = kt * 64;
    const int tid = threadIdx.x;
    const int tx = tid & 15;       // q frag: tx*4 + i
    const int ty = tid >> 4;       // k frag: ty*4 + j   (0..15)
    const int w  = tid >> 6;
    const int lane = tid & 63;

    Wv2[tid] = wvp[tid] * (2.0f * LOG2E);   // blockDim == H == 256

    const int mq = b * LQ + qb;
    const int mk = b * LK + kb;
    const int sh = tid >> 4;       // staging row 0..15 (+16 steps)
    const int sm = (tid & 15) * 4;

    float acc[4][4] = {};

    for (int h0 = 0; h0 < H; h0 += 64) {
        __syncthreads();   // also covers the Wv2 write on the first pass
#pragma unroll
        for (int it = 0; it < 4; ++it) {
            int h = sh + 16 * it;
            *(float4*)&Qs[h][sm] = *(const float4*)(EqT + (size_t)(h0 + h) * M + mq + sm);
            *(float4*)&Ks[h][sm] = *(const float4*)(EkT + (size_t)(h0 + h) * M + mk + sm);
        }
        __syncthreads();
#pragma unroll 8
        for (int hh = 0; hh < 64; hh += 2) {
            float4 q1 = *(const float4*)&Qs[hh][tx * 4];
            float4 q2 = *(const float4*)&Qs[hh + 1][tx * 4];
            float4 k1 = *(const float4*)&Ks[hh][ty * 4];
            float4 k2 = *(const float4*)&Ks[hh + 1][ty * 4];
            float2 w12 = *(const float2*)&Wv2[h0 + hh];
            const float w1 = w12.x, w2 = w12.y;
            const float q1a[4] = {q1.x, q1.y, q1.z, q1.w};
            const float q2a[4] = {q2.x, q2.y, q2.z, q2.w};
            const float k1a[4] = {k1.x, k1.y, k1.z, k1.w};
            const float k2a[4] = {k2.x, k2.y, k2.z, k2.w};
#pragma unroll
            for (int i = 0; i < 4; ++i)
#pragma unroll
                for (int j = 0; j < 4; ++j) {
                    float ta = fmaf(q1a[i], k1a[j], 1.0f);
                    float tb = fmaf(q2a[i], k2a[j], 1.0f);
                    float num = fmaf(w1, tb, w2 * ta);
                    acc[i][j] = fmaf(num, __builtin_amdgcn_rcpf(ta * tb), acc[i][j]);
                }
        }
    }

    // Epilogue: P = exp2(-acc) -> bf16 Pq[b][q][kb+ty*4..+3]; row partials.
    float ps[4];
#pragma unroll
    for (int i = 0; i < 4; ++i) {
        int q = qb + tx * 4 + i;
        float p0 = __builtin_amdgcn_exp2f(-acc[i][0]);
        float p1 = __builtin_amdgcn_exp2f(-acc[i][1]);
        float p2 = __builtin_amdgcn_exp2f(-acc[i][2]);
        float p3 = __builtin_amdgcn_exp2f(-acc[i][3]);
        ps[i] = (p0 + p1) + (p2 + p3);
        uint2 o = { pk2(p0, p1), pk2(p2, p3) };
        *(uint2*)(Pq + ((size_t)(b * 512 + q) * 512 + kb + ty * 4)) = o;
    }
#pragma unroll
    for (int i = 0; i < 4; ++i) {
        ps[i] += __shfl_xor(ps[i], 16, 64);
        ps[i] += __shfl_xor(ps[i], 32, 64);
    }
    if (lane < 16) {
#pragma unroll
        for (int i = 0; i < 4; ++i) redS[w][tx * 4 + i] = ps[i];
    }
    __syncthreads();
    if (tid < 64) {
        float s = (redS[0][tid] + redS[1][tid]) + (redS[2][tid] + redS[3][tid]);
        rowpart[(size_t)kt * 2048 + b * 512 + qb + tid] = s;
    }
}

// ---------------------------------------------------------------------------
// Kernel C: out = (P @ V) / rowsum via bf16 MFMA.  (unchanged from R9/R10)
// ---------------------------------------------------------------------------
__global__ __launch_bounds__(256) void av_mfma(
    const float* __restrict__ V, const char* __restrict__ wsc,
    float* __restrict__ O)
{
    const unsigned short* Pq = (const unsigned short*)(wsc + OFF_PQ);
    const float* rowpart = (const float*)(wsc + OFF_ROW);

    __shared__ unsigned short Pls[64][136];
    __shared__ unsigned short Vls[64][136];

    const int b = blockIdx.z, qb = blockIdx.x * 64, nb = blockIdx.y * 64;
    const int tid = threadIdx.x;
    const int wid = tid >> 6, lane = tid & 63;
    const int ml = lane & 15, quad = lane >> 4;
    const unsigned short* Pb = Pq + (size_t)b * 512 * 512;
    const float* Vb = V + (size_t)b * 512 * 512;

    f32x4v acc[4] = {{0,0,0,0},{0,0,0,0},{0,0,0,0},{0,0,0,0}};

    for (int kc = 0; kc < LK; kc += 128) {
        __syncthreads();
#pragma unroll
        for (int it = 0; it < 4; ++it) {
            int u = tid + it * 256;
            int row = u >> 4, c8 = (u & 15) * 8;
            *(uint4*)&Pls[row][c8] = *(const uint4*)(Pb + (size_t)(qb + row) * 512 + kc + c8);
        }
#pragma unroll
        for (int it = 0; it < 8; ++it) {
            int u = tid + it * 256;           // 2048 float4 units
            int k = u >> 4, c4 = (u & 15) * 4;
            float4 v4 = *(const float4*)(Vb + (size_t)(kc + k) * 512 + nb + c4);
            Vls[c4 + 0][k] = f2bf(v4.x);
            Vls[c4 + 1][k] = f2bf(v4.y);
            Vls[c4 + 2][k] = f2bf(v4.z);
            Vls[c4 + 3][k] = f2bf(v4.w);
        }
        __syncthreads();
#pragma unroll
        for (int s = 0; s < 4; ++s) {
            int k = s * 32 + quad * 8;
            bf16x8 af = *(const bf16x8*)&Pls[wid * 16 + ml][k];
#pragma unroll
            for (int nt = 0; nt < 4; ++nt) {
                bf16x8 bfr = *(const bf16x8*)&Vls[nt * 16 + ml][k];
                acc[nt] = __builtin_amdgcn_mfma_f32_16x16x32_bf16(af, bfr, acc[nt], 0, 0, 0);
            }
        }
    }

    float rr[4];
#pragma unroll
    for (int r = 0; r < 4; ++r) {
        int q = qb + wid * 16 + quad * 4 + r;
        float rs = 0.f;
#pragma unroll
        for (int t = 0; t < 8; ++t) rs += rowpart[(size_t)t * 2048 + b * 512 + q];
        rr[r] = 1.0f / rs;
    }
#pragma unroll
    for (int nt = 0; nt < 4; ++nt)
#pragma unroll
        for (int r = 0; r < 4; ++r) {
            int q = qb + wid * 16 + quad * 4 + r;
            O[((size_t)b * 512 + q) * 512 + nb + nt * 16 + ml] = acc[nt][r] * rr[r];
        }
}

extern "C" void kernel_launch(void* const* d_in, const int* in_sizes, int n_in,
                              void* d_out, int out_size, void* d_ws, size_t ws_size,
                              hipStream_t stream) {
    const float* query = (const float*)d_in[0];
    const float* key   = (const float*)d_in[1];
    const float* value = (const float*)d_in[2];
    const float* wq    = (const float*)d_in[3];
    const float* bq    = (const float*)d_in[4];
    const float* wk    = (const float*)d_in[5];
    const float* bk    = (const float*)d_in[6];
    const float* wv    = (const float*)d_in[7];
    // d_in[8] = bv: row-constant -> softmax-invariant, dropped.
    float* out = (float*)d_out;
    char* ws = (char*)d_ws;

    const float c2 = 2.0f * LOG2E;

    proj_mfma<<<dim3(32, 4, 2), 256, 0, stream>>>(query, key, wq, wk, bq, bk, ws, c2);
    score_kernel<<<dim3(8, 8, Bb), 256, 0, stream>>>(wv, ws);
    av_mfma<<<dim3(8, 8, Bb), 256, 0, stream>>>(value, ws, out);
}

// Round 13
// 140.579 us; speedup vs baseline: 1.0620x; 1.0027x over previous
//
#include <hip/hip_runtime.h>

#define LOG2E 1.4426950408889634f

// Problem constants
constexpr int Bb = 4, LQ = 512, LK = 512, QS = 512, H = 256, DV = 512;
constexpr int M = 2048;   // B*LQ

// Workspace byte offsets
constexpr size_t OFF_EQT = 0;            // [256][2048] f32 (2 MiB) exp2-domain q proj
constexpr size_t OFF_EKT = 2u << 20;     // [256][2048] f32 (2 MiB)
constexpr size_t OFF_PQ  = 4u << 20;     // [4][512][512] bf16 (2 MiB) P numerators
constexpr size_t OFF_ROW = 6u << 20;     // [8][2048] f32 rowsum partials

using bf16x8 = __attribute__((ext_vector_type(8))) short;
using f32x4v = __attribute__((ext_vector_type(4))) float;

__device__ inline unsigned short f2bf(float x) {
    unsigned int u = __float_as_uint(x);
    u += 0x7FFFu + ((u >> 16) & 1u);      // round-to-nearest-even
    return (unsigned short)(u >> 16);
}
__device__ inline unsigned int pk2(float lo, float hi) {
    return (unsigned int)f2bf(lo) | ((unsigned int)f2bf(hi) << 16);
}

// ---------------------------------------------------------------------------
// Kernel A: proj via bf16 MFMA + exp2 epilogue, transposed fp32 output.
//   EqT[n][m] = exp2( clamp( scale*(A[m]·W[n] + bias[n]), ±30 ) )
// (unchanged from R9/R10 — measured fast)
// ---------------------------------------------------------------------------
__global__ __launch_bounds__(256) void proj_mfma(
    const float* __restrict__ query, const float* __restrict__ key,
    const float* __restrict__ wq, const float* __restrict__ wk,
    const float* __restrict__ bq, const float* __restrict__ bk,
    char* __restrict__ ws, float scale)
{
    const int z = blockIdx.z;
    const float* A    = z ? key : query;   // [2048][512]
    const float* W    = z ? wk : wq;       // [256][512]
    const float* bias = z ? bk : bq;
    float* out = (float*)(ws + (z ? OFF_EKT : OFF_EQT));   // [256][2048]

    __shared__ unsigned short Als[64][136];
    __shared__ unsigned short Wls[64][136];
    __shared__ float Ot[64][68];

    const int mb = blockIdx.x * 64, nb = blockIdx.y * 64;
    const int tid = threadIdx.x;
    const int wid = tid >> 6, lane = tid & 63;
    const int ml = lane & 15, quad = lane >> 4;

    f32x4v acc[4] = {{0,0,0,0},{0,0,0,0},{0,0,0,0},{0,0,0,0}};

    for (int kc = 0; kc < QS; kc += 128) {
        __syncthreads();
#pragma unroll
        for (int it = 0; it < 4; ++it) {
            int u = tid + it * 256;          // 0..1023 units of 8 elems
            int row = u >> 4, c8 = (u & 15) * 8;
            float4 a0 = *(const float4*)(A + (size_t)(mb + row) * 512 + kc + c8);
            float4 a1 = *(const float4*)(A + (size_t)(mb + row) * 512 + kc + c8 + 4);
            uint4 pa = { pk2(a0.x, a0.y), pk2(a0.z, a0.w), pk2(a1.x, a1.y), pk2(a1.z, a1.w) };
            *(uint4*)&Als[row][c8] = pa;
            float4 w0 = *(const float4*)(W + (size_t)(nb + row) * 512 + kc + c8);
            float4 w1 = *(const float4*)(W + (size_t)(nb + row) * 512 + kc + c8 + 4);
            uint4 pw = { pk2(w0.x, w0.y), pk2(w0.z, w0.w), pk2(w1.x, w1.y), pk2(w1.z, w1.w) };
            *(uint4*)&Wls[row][c8] = pw;
        }
        __syncthreads();
#pragma unroll
        for (int s = 0; s < 4; ++s) {
            int k = s * 32 + quad * 8;
            bf16x8 af = *(const bf16x8*)&Als[wid * 16 + ml][k];
#pragma unroll
            for (int nt = 0; nt < 4; ++nt) {
                bf16x8 bfr = *(const bf16x8*)&Wls[nt * 16 + ml][k];
                acc[nt] = __builtin_amdgcn_mfma_f32_16x16x32_bf16(af, bfr, acc[nt], 0, 0, 0);
            }
        }
    }
    __syncthreads();
#pragma unroll
    for (int nt = 0; nt < 4; ++nt)
#pragma unroll
        for (int r = 0; r < 4; ++r)
            Ot[nt * 16 + ml][wid * 16 + quad * 4 + r] = acc[nt][r];
    __syncthreads();
    {
        int r0 = tid >> 2;            // n-local 0..63
        int c0 = (tid & 3) * 16;      // m-local base
        float bs = bias[nb + r0];
#pragma unroll
        for (int g = 0; g < 4; ++g) {
            float4 v = *(const float4*)&Ot[r0][c0 + g * 4];
            float4 o;
            o.x = __builtin_amdgcn_exp2f(fminf(fmaxf(scale * (v.x + bs), -30.f), 30.f));
            o.y = __builtin_amdgcn_exp2f(fminf(fmaxf(scale * (v.y + bs), -30.f), 30.f));
            o.z = __builtin_amdgcn_exp2f(fminf(fmaxf(scale * (v.z + bs), -30.f), 30.f));
            o.w = __builtin_amdgcn_exp2f(fminf(fmaxf(scale * (v.w + bs), -30.f), 30.f));
            *(float4*)(out + (size_t)(nb + r0) * 2048 + mb + c0 + g * 4) = o;
        }
    }
}

// ---------------------------------------------------------------------------
// Kernel B: scores -> P = exp2(-acc) bf16 [b][q][k] + per-ktile row partials.
//   acc(q,k) = sum_h Wv2[h]/(1 + Eq[h][q]*Ek[h][k]),  h-terms paired
//   (one rcp per two h — rcp is the quarter-rate trans pipe).
// R13 change: __launch_bounds__(256, 1).  The 256-block grid gives only
// 1 wave/SIMD, so the default high-occupancy VGPR target (52 regs) is pure
// waste — it forces the compiler to serialize the 16 independent rcp chains.
// Declaring 1 wave/EU raises the VGPR cap to ~512 so all chains stay live
// and ds_reads can be hoisted.  Code otherwise identical to R12.
// ---------------------------------------------------------------------------
__global__ __launch_bounds__(256, 1) void score_kernel(
    const float* __restrict__ wvp, char* __restrict__ ws)
{
    const float* EqT = (const float*)(ws + OFF_EQT);   // [256][2048]
    const float* EkT = (const float*)(ws + OFF_EKT);
    unsigned short* Pq = (unsigned short*)(ws + OFF_PQ);  // [4][512][512] bf16
    float* rowpart = (float*)(ws + OFF_ROW);              // [8][2048]

    __shared__ float Qs[64][64];
    __shared__ float Ks[64][64];
    __shared__ float Wv2[H];
    __shared__ float redS[4][64];

    const int b  = blockIdx.z;
    const int qb = blockIdx.x * 64;
    const int kt = blockIdx.y;
    const int kb = kt * 64;
    const int tid = threadIdx.x;
    const int tx = tid & 15;       // q frag: tx*4 + i
    const int ty = tid >> 4;       // k frag: ty*4 + j   (0..15)
    const int w  = tid >> 6;
    const int lane = tid & 63;

    Wv2[tid] = wvp[tid] * (2.0f * LOG2E);   // blockDim == H == 256

    const int mq = b * LQ + qb;
    const int mk = b * LK + kb;
    const int sh = tid >> 4;       // staging row 0..15 (+16 steps)
    const int sm = (tid & 15) * 4;

    float acc[4][4] = {};

    for (int h0 = 0; h0 < H; h0 += 64) {
        __syncthreads();   // also covers the Wv2 write on the first pass
#pragma unroll
        for (int it = 0; it < 4; ++it) {
            int h = sh + 16 * it;
            *(float4*)&Qs[h][sm] = *(const float4*)(EqT + (size_t)(h0 + h) * M + mq + sm);
            *(float4*)&Ks[h][sm] = *(const float4*)(EkT + (size_t)(h0 + h) * M + mk + sm);
        }
        __syncthreads();
#pragma unroll 8
        for (int hh = 0; hh < 64; hh += 2) {
            float4 q1 = *(const float4*)&Qs[hh][tx * 4];
            float4 q2 = *(const float4*)&Qs[hh + 1][tx * 4];
            float4 k1 = *(const float4*)&Ks[hh][ty * 4];
            float4 k2 = *(const float4*)&Ks[hh + 1][ty * 4];
            float2 w12 = *(const float2*)&Wv2[h0 + hh];
            const float w1 = w12.x, w2 = w12.y;
            const float q1a[4] = {q1.x, q1.y, q1.z, q1.w};
            const float q2a[4] = {q2.x, q2.y, q2.z, q2.w};
            const float k1a[4] = {k1.x, k1.y, k1.z, k1.w};
            const float k2a[4] = {k2.x, k2.y, k2.z, k2.w};
#pragma unroll
            for (int i = 0; i < 4; ++i)
#pragma unroll
                for (int j = 0; j < 4; ++j) {
                    float ta = fmaf(q1a[i], k1a[j], 1.0f);
                    float tb = fmaf(q2a[i], k2a[j], 1.0f);
                    float num = fmaf(w1, tb, w2 * ta);
                    acc[i][j] = fmaf(num, __builtin_amdgcn_rcpf(ta * tb), acc[i][j]);
                }
        }
    }

    // Epilogue: P = exp2(-acc) -> bf16 Pq[b][q][kb+ty*4..+3]; row partials.
    float ps[4];
#pragma unroll
    for (int i = 0; i < 4; ++i) {
        int q = qb + tx * 4 + i;
        float p0 = __builtin_amdgcn_exp2f(-acc[i][0]);
        float p1 = __builtin_amdgcn_exp2f(-acc[i][1]);
        float p2 = __builtin_amdgcn_exp2f(-acc[i][2]);
        float p3 = __builtin_amdgcn_exp2f(-acc[i][3]);
        ps[i] = (p0 + p1) + (p2 + p3);
        uint2 o = { pk2(p0, p1), pk2(p2, p3) };
        *(uint2*)(Pq + ((size_t)(b * 512 + q) * 512 + kb + ty * 4)) = o;
    }
#pragma unroll
    for (int i = 0; i < 4; ++i) {
        ps[i] += __shfl_xor(ps[i], 16, 64);
        ps[i] += __shfl_xor(ps[i], 32, 64);
    }
    if (lane < 16) {
#pragma unroll
        for (int i = 0; i < 4; ++i) redS[w][tx * 4 + i] = ps[i];
    }
    __syncthreads();
    if (tid < 64) {
        float s = (redS[0][tid] + redS[1][tid]) + (redS[2][tid] + redS[3][tid]);
        rowpart[(size_t)kt * 2048 + b * 512 + qb + tid] = s;
    }
}

// ---------------------------------------------------------------------------
// Kernel C: out = (P @ V) / rowsum via bf16 MFMA.  (unchanged from R9/R10)
// ---------------------------------------------------------------------------
__global__ __launch_bounds__(256) void av_mfma(
    const float* __restrict__ V, const char* __restrict__ wsc,
    float* __restrict__ O)
{
    const unsigned short* Pq = (const unsigned short*)(wsc + OFF_PQ);
    const float* rowpart = (const float*)(wsc + OFF_ROW);

    __shared__ unsigned short Pls[64][136];
    __shared__ unsigned short Vls[64][136];

    const int b = blockIdx.z, qb = blockIdx.x * 64, nb = blockIdx.y * 64;
    const int tid = threadIdx.x;
    const int wid = tid >> 6, lane = tid & 63;
    const int ml = lane & 15, quad = lane >> 4;
    const unsigned short* Pb = Pq + (size_t)b * 512 * 512;
    const float* Vb = V + (size_t)b * 512 * 512;

    f32x4v acc[4] = {{0,0,0,0},{0,0,0,0},{0,0,0,0},{0,0,0,0}};

    for (int kc = 0; kc < LK; kc += 128) {
        __syncthreads();
#pragma unroll
        for (int it = 0; it < 4; ++it) {
            int u = tid + it * 256;
            int row = u >> 4, c8 = (u & 15) * 8;
            *(uint4*)&Pls[row][c8] = *(const uint4*)(Pb + (size_t)(qb + row) * 512 + kc + c8);
        }
#pragma unroll
        for (int it = 0; it < 8; ++it) {
            int u = tid + it * 256;           // 2048 float4 units
            int k = u >> 4, c4 = (u & 15) * 4;
            float4 v4 = *(const float4*)(Vb + (size_t)(kc + k) * 512 + nb + c4);
            Vls[c4 + 0][k] = f2bf(v4.x);
            Vls[c4 + 1][k] = f2bf(v4.y);
            Vls[c4 + 2][k] = f2bf(v4.z);
            Vls[c4 + 3][k] = f2bf(v4.w);
        }
        __syncthreads();
#pragma unroll
        for (int s = 0; s < 4; ++s) {
            int k = s * 32 + quad * 8;
            bf16x8 af = *(const bf16x8*)&Pls[wid * 16 + ml][k];
#pragma unroll
            for (int nt = 0; nt < 4; ++nt) {
                bf16x8 bfr = *(const bf16x8*)&Vls[nt * 16 + ml][k];
                acc[nt] = __builtin_amdgcn_mfma_f32_16x16x32_bf16(af, bfr, acc[nt], 0, 0, 0);
            }
        }
    }

    float rr[4];
#pragma unroll
    for (int r = 0; r < 4; ++r) {
        int q = qb + wid * 16 + quad * 4 + r;
        float rs = 0.f;
#pragma unroll
        for (int t = 0; t < 8; ++t) rs += rowpart[(size_t)t * 2048 + b * 512 + q];
        rr[r] = 1.0f / rs;
    }
#pragma unroll
    for (int nt = 0; nt < 4; ++nt)
#pragma unroll
        for (int r = 0; r < 4; ++r) {
            int q = qb + wid * 16 + quad * 4 + r;
            O[((size_t)b * 512 + q) * 512 + nb + nt * 16 + ml] = acc[nt][r] * rr[r];
        }
}

extern "C" void kernel_launch(void* const* d_in, const int* in_sizes, int n_in,
                              void* d_out, int out_size, void* d_ws, size_t ws_size,
                              hipStream_t stream) {
    const float* query = (const float*)d_in[0];
    const float* key   = (const float*)d_in[1];
    const float* value = (const float*)d_in[2];
    const float* wq    = (const float*)d_in[3];
    const float* bq    = (const float*)d_in[4];
    const float* wk    = (const float*)d_in[5];
    const float* bk    = (const float*)d_in[6];
    const float* wv    = (const float*)d_in[7];
    // d_in[8] = bv: row-constant -> softmax-invariant, dropped.
    float* out = (float*)d_out;
    char* ws = (char*)d_ws;

    const float c2 = 2.0f * LOG2E;

    proj_mfma<<<dim3(32, 4, 2), 256, 0, stream>>>(query, key, wq, wk, bq, bk, ws, c2);
    score_kernel<<<dim3(8, 8, Bb), 256, 0, stream>>>(wv, ws);
    av_mfma<<<dim3(8, 8, Bb), 256, 0, stream>>>(value, ws, out);
}

// Round 14
// 138.825 us; speedup vs baseline: 1.0754x; 1.0126x over previous
//
#include <hip/hip_runtime.h>

#define LOG2E 1.4426950408889634f

// Problem constants
constexpr int Bb = 4, LQ = 512, LK = 512, QS = 512, H = 256, DV = 512;
constexpr int M = 2048;   // B*LQ

// Workspace byte offsets
constexpr size_t OFF_EQT = 0;            // [256][2048] f32 (2 MiB) exp2-domain q proj
constexpr size_t OFF_EKT = 2u << 20;     // [256][2048] f32 (2 MiB)
constexpr size_t OFF_PQ  = 4u << 20;     // [4][512][512] bf16 (2 MiB) P numerators
constexpr size_t OFF_ROW = 6u << 20;     // [8][2048] f32 rowsum partials

using bf16x8 = __attribute__((ext_vector_type(8))) short;
using f32x4v = __attribute__((ext_vector_type(4))) float;

__device__ inline unsigned short f2bf(float x) {
    unsigned int u = __float_as_uint(x);
    u += 0x7FFFu + ((u >> 16) & 1u);      // round-to-nearest-even
    return (unsigned short)(u >> 16);
}
__device__ inline unsigned int pk2(float lo, float hi) {
    return (unsigned int)f2bf(lo) | ((unsigned int)f2bf(hi) << 16);
}

// ---------------------------------------------------------------------------
// Kernel A: proj via bf16 MFMA + exp2 epilogue, transposed fp32 output.
//   EqT[n][m] = exp2( clamp( scale*(A[m]·W[n] + bias[n]), ±15 ) )
// Clamp is ±15 (was ±30) so the score kernel's QUAD den t1·t2·t3·t4 stays
// <= ~2^121 < fp32 max.  tanh clamp error 6e-5 on <0.01% of elements —
// negligible after wv weighting.  (otherwise unchanged from R9)
// ---------------------------------------------------------------------------
__global__ __launch_bounds__(256) void proj_mfma(
    const float* __restrict__ query, const float* __restrict__ key,
    const float* __restrict__ wq, const float* __restrict__ wk,
    const float* __restrict__ bq, const float* __restrict__ bk,
    char* __restrict__ ws, float scale)
{
    const int z = blockIdx.z;
    const float* A    = z ? key : query;   // [2048][512]
    const float* W    = z ? wk : wq;       // [256][512]
    const float* bias = z ? bk : bq;
    float* out = (float*)(ws + (z ? OFF_EKT : OFF_EQT));   // [256][2048]

    __shared__ unsigned short Als[64][136];
    __shared__ unsigned short Wls[64][136];
    __shared__ float Ot[64][68];

    const int mb = blockIdx.x * 64, nb = blockIdx.y * 64;
    const int tid = threadIdx.x;
    const int wid = tid >> 6, lane = tid & 63;
    const int ml = lane & 15, quad = lane >> 4;

    f32x4v acc[4] = {{0,0,0,0},{0,0,0,0},{0,0,0,0},{0,0,0,0}};

    for (int kc = 0; kc < QS; kc += 128) {
        __syncthreads();
#pragma unroll
        for (int it = 0; it < 4; ++it) {
            int u = tid + it * 256;          // 0..1023 units of 8 elems
            int row = u >> 4, c8 = (u & 15) * 8;
            float4 a0 = *(const float4*)(A + (size_t)(mb + row) * 512 + kc + c8);
            float4 a1 = *(const float4*)(A + (size_t)(mb + row) * 512 + kc + c8 + 4);
            uint4 pa = { pk2(a0.x, a0.y), pk2(a0.z, a0.w), pk2(a1.x, a1.y), pk2(a1.z, a1.w) };
            *(uint4*)&Als[row][c8] = pa;
            float4 w0 = *(const float4*)(W + (size_t)(nb + row) * 512 + kc + c8);
            float4 w1 = *(const float4*)(W + (size_t)(nb + row) * 512 + kc + c8 + 4);
            uint4 pw = { pk2(w0.x, w0.y), pk2(w0.z, w0.w), pk2(w1.x, w1.y), pk2(w1.z, w1.w) };
            *(uint4*)&Wls[row][c8] = pw;
        }
        __syncthreads();
#pragma unroll
        for (int s = 0; s < 4; ++s) {
            int k = s * 32 + quad * 8;
            bf16x8 af = *(const bf16x8*)&Als[wid * 16 + ml][k];
#pragma unroll
            for (int nt = 0; nt < 4; ++nt) {
                bf16x8 bfr = *(const bf16x8*)&Wls[nt * 16 + ml][k];
                acc[nt] = __builtin_amdgcn_mfma_f32_16x16x32_bf16(af, bfr, acc[nt], 0, 0, 0);
            }
        }
    }
    __syncthreads();
#pragma unroll
    for (int nt = 0; nt < 4; ++nt)
#pragma unroll
        for (int r = 0; r < 4; ++r)
            Ot[nt * 16 + ml][wid * 16 + quad * 4 + r] = acc[nt][r];
    __syncthreads();
    {
        int r0 = tid >> 2;            // n-local 0..63
        int c0 = (tid & 3) * 16;      // m-local base
        float bs = bias[nb + r0];
#pragma unroll
        for (int g = 0; g < 4; ++g) {
            float4 v = *(const float4*)&Ot[r0][c0 + g * 4];
            float4 o;
            o.x = __builtin_amdgcn_exp2f(fminf(fmaxf(scale * (v.x + bs), -15.f), 15.f));
            o.y = __builtin_amdgcn_exp2f(fminf(fmaxf(scale * (v.y + bs), -15.f), 15.f));
            o.z = __builtin_amdgcn_exp2f(fminf(fmaxf(scale * (v.z + bs), -15.f), 15.f));
            o.w = __builtin_amdgcn_exp2f(fminf(fmaxf(scale * (v.w + bs), -15.f), 15.f));
            *(float4*)(out + (size_t)(nb + r0) * 2048 + mb + c0 + g * 4) = o;
        }
    }
}

// ---------------------------------------------------------------------------
// Kernel B: scores -> P = exp2(-acc) bf16 [b][q][k] + per-ktile row partials.
//   acc(q,k) = sum_h Wv2[h]/(1 + Eq[h][q]*Ek[h][k])
// R14: QUAD-pairing — one rcp per FOUR h-terms:
//   w1/ta+w2/tb+w3/tc+w4/td = ((w1·tb+w2·ta)·t34 + (w3·td+w4·tc)·t12)
//                              / (t12·t34),   t12=ta·tb, t34=tc·td
// Per 4 elems: 14 VALU + 1 rcp (vs 12 + 2).  rcp issue-accounting (16
// cyc/wave64 at quarter rate) showed trans was the dominant pipe — this
// halves it.  den <= ~2^121 (proj clamp ±15).  Grid (8,8,4), 256 thr.
// ---------------------------------------------------------------------------
__global__ __launch_bounds__(256, 1) void score_kernel(
    const float* __restrict__ wvp, char* __restrict__ ws)
{
    const float* EqT = (const float*)(ws + OFF_EQT);   // [256][2048]
    const float* EkT = (const float*)(ws + OFF_EKT);
    unsigned short* Pq = (unsigned short*)(ws + OFF_PQ);  // [4][512][512] bf16
    float* rowpart = (float*)(ws + OFF_ROW);              // [8][2048]

    __shared__ float Qs[64][64];
    __shared__ float Ks[64][64];
    __shared__ float Wv2[H];
    __shared__ float redS[4][64];

    const int b  = blockIdx.z;
    const int qb = blockIdx.x * 64;
    const int kt = blockIdx.y;
    const int kb = kt * 64;
    const int tid = threadIdx.x;
    const int tx = tid & 15;       // q frag: tx*4 + i
    const int ty = tid >> 4;       // k frag: ty*4 + j   (0..15)
    const int w  = tid >> 6;
    const int lane = tid & 63;

    Wv2[tid] = wvp[tid] * (2.0f * LOG2E);   // blockDim == H == 256

    const int mq = b * LQ + qb;
    const int mk = b * LK + kb;
    const int sh = tid >> 4;       // staging row 0..15 (+16 steps)
    const int sm = (tid & 15) * 4;

    float acc[4][4] = {};

    for (int h0 = 0; h0 < H; h0 += 64) {
        __syncthreads();   // also covers the Wv2 write on the first pass
#pragma unroll
        for (int it = 0; it < 4; ++it) {
            int h = sh + 16 * it;
            *(float4*)&Qs[h][sm] = *(const float4*)(EqT + (size_t)(h0 + h) * M + mq + sm);
            *(float4*)&Ks[h][sm] = *(const float4*)(EkT + (size_t)(h0 + h) * M + mk + sm);
        }
        __syncthreads();
#pragma unroll 4
        for (int hh = 0; hh < 64; hh += 4) {
            float4 q1 = *(const float4*)&Qs[hh][tx * 4];
            float4 q2 = *(const float4*)&Qs[hh + 1][tx * 4];
            float4 q3 = *(const float4*)&Qs[hh + 2][tx * 4];
            float4 q4 = *(const float4*)&Qs[hh + 3][tx * 4];
            float4 k1 = *(const float4*)&Ks[hh][ty * 4];
            float4 k2 = *(const float4*)&Ks[hh + 1][ty * 4];
            float4 k3 = *(const float4*)&Ks[hh + 2][ty * 4];
            float4 k4 = *(const float4*)&Ks[hh + 3][ty * 4];
            float4 w4v = *(const float4*)&Wv2[h0 + hh];
            const float w1 = w4v.x, w2 = w4v.y, w3 = w4v.z, w4 = w4v.w;
            const float q1a[4] = {q1.x, q1.y, q1.z, q1.w};
            const float q2a[4] = {q2.x, q2.y, q2.z, q2.w};
            const float q3a[4] = {q3.x, q3.y, q3.z, q3.w};
            const float q4a[4] = {q4.x, q4.y, q4.z, q4.w};
            const float k1a[4] = {k1.x, k1.y, k1.z, k1.w};
            const float k2a[4] = {k2.x, k2.y, k2.z, k2.w};
            const float k3a[4] = {k3.x, k3.y, k3.z, k3.w};
            const float k4a[4] = {k4.x, k4.y, k4.z, k4.w};
#pragma unroll
            for (int i = 0; i < 4; ++i)
#pragma unroll
                for (int j = 0; j < 4; ++j) {
                    float ta = fmaf(q1a[i], k1a[j], 1.0f);
                    float tb = fmaf(q2a[i], k2a[j], 1.0f);
                    float tc = fmaf(q3a[i], k3a[j], 1.0f);
                    float td = fmaf(q4a[i], k4a[j], 1.0f);
                    float t12 = ta * tb;
                    float t34 = tc * td;
                    float n12 = fmaf(w1, tb, w2 * ta);
                    float n34 = fmaf(w3, td, w4 * tc);
                    float num = fmaf(n12, t34, n34 * t12);
                    float den = t12 * t34;
                    acc[i][j] = fmaf(num, __builtin_amdgcn_rcpf(den), acc[i][j]);
                }
        }
    }

    // Epilogue: P = exp2(-acc) -> bf16 Pq[b][q][kb+ty*4..+3]; row partials.
    float ps[4];
#pragma unroll
    for (int i = 0; i < 4; ++i) {
        int q = qb + tx * 4 + i;
        float p0 = __builtin_amdgcn_exp2f(-acc[i][0]);
        float p1 = __builtin_amdgcn_exp2f(-acc[i][1]);
        float p2 = __builtin_amdgcn_exp2f(-acc[i][2]);
        float p3 = __builtin_amdgcn_exp2f(-acc[i][3]);
        ps[i] = (p0 + p1) + (p2 + p3);
        uint2 o = { pk2(p0, p1), pk2(p2, p3) };
        *(uint2*)(Pq + ((size_t)(b * 512 + q) * 512 + kb + ty * 4)) = o;
    }
#pragma unroll
    for (int i = 0; i < 4; ++i) {
        ps[i] += __shfl_xor(ps[i], 16, 64);
        ps[i] += __shfl_xor(ps[i], 32, 64);
    }
    if (lane < 16) {
#pragma unroll
        for (int i = 0; i < 4; ++i) redS[w][tx * 4 + i] = ps[i];
    }
    __syncthreads();
    if (tid < 64) {
        float s = (redS[0][tid] + redS[1][tid]) + (redS[2][tid] + redS[3][tid]);
        rowpart[(size_t)kt * 2048 + b * 512 + qb + tid] = s;
    }
}

// ---------------------------------------------------------------------------
// Kernel C: out = (P @ V) / rowsum via bf16 MFMA.  (unchanged from R9/R10)
// ---------------------------------------------------------------------------
__global__ __launch_bounds__(256) void av_mfma(
    const float* __restrict__ V, const char* __restrict__ wsc,
    float* __restrict__ O)
{
    const unsigned short* Pq = (const unsigned short*)(wsc + OFF_PQ);
    const float* rowpart = (const float*)(wsc + OFF_ROW);

    __shared__ unsigned short Pls[64][136];
    __shared__ unsigned short Vls[64][136];

    const int b = blockIdx.z, qb = blockIdx.x * 64, nb = blockIdx.y * 64;
    const int tid = threadIdx.x;
    const int wid = tid >> 6, lane = tid & 63;
    const int ml = lane & 15, quad = lane >> 4;
    const unsigned short* Pb = Pq + (size_t)b * 512 * 512;
    const float* Vb = V + (size_t)b * 512 * 512;

    f32x4v acc[4] = {{0,0,0,0},{0,0,0,0},{0,0,0,0},{0,0,0,0}};

    for (int kc = 0; kc < LK; kc += 128) {
        __syncthreads();
#pragma unroll
        for (int it = 0; it < 4; ++it) {
            int u = tid + it * 256;
            int row = u >> 4, c8 = (u & 15) * 8;
            *(uint4*)&Pls[row][c8] = *(const uint4*)(Pb + (size_t)(qb + row) * 512 + kc + c8);
        }
#pragma unroll
        for (int it = 0; it < 8; ++it) {
            int u = tid + it * 256;           // 2048 float4 units
            int k = u >> 4, c4 = (u & 15) * 4;
            float4 v4 = *(const float4*)(Vb + (size_t)(kc + k) * 512 + nb + c4);
            Vls[c4 + 0][k] = f2bf(v4.x);
            Vls[c4 + 1][k] = f2bf(v4.y);
            Vls[c4 + 2][k] = f2bf(v4.z);
            Vls[c4 + 3][k] = f2bf(v4.w);
        }
        __syncthreads();
#pragma unroll
        for (int s = 0; s < 4; ++s) {
            int k = s * 32 + quad * 8;
            bf16x8 af = *(const bf16x8*)&Pls[wid * 16 + ml][k];
#pragma unroll
            for (int nt = 0; nt < 4; ++nt) {
                bf16x8 bfr = *(const bf16x8*)&Vls[nt * 16 + ml][k];
                acc[nt] = __builtin_amdgcn_mfma_f32_16x16x32_bf16(af, bfr, acc[nt], 0, 0, 0);
            }
        }
    }

    float rr[4];
#pragma unroll
    for (int r = 0; r < 4; ++r) {
        int q = qb + wid * 16 + quad * 4 + r;
        float rs = 0.f;
#pragma unroll
        for (int t = 0; t < 8; ++t) rs += rowpart[(size_t)t * 2048 + b * 512 + q];
        rr[r] = 1.0f / rs;
    }
#pragma unroll
    for (int nt = 0; nt < 4; ++nt)
#pragma unroll
        for (int r = 0; r < 4; ++r) {
            int q = qb + wid * 16 + quad * 4 + r;
            O[((size_t)b * 512 + q) * 512 + nb + nt * 16 + ml] = acc[nt][r] * rr[r];
        }
}

extern "C" void kernel_launch(void* const* d_in, const int* in_sizes, int n_in,
                              void* d_out, int out_size, void* d_ws, size_t ws_size,
                              hipStream_t stream) {
    const float* query = (const float*)d_in[0];
    const float* key   = (const float*)d_in[1];
    const float* value = (const float*)d_in[2];
    const float* wq    = (const float*)d_in[3];
    const float* bq    = (const float*)d_in[4];
    const float* wk    = (const float*)d_in[5];
    const float* bk    = (const float*)d_in[6];
    const float* wv    = (const float*)d_in[7];
    // d_in[8] = bv: row-constant -> softmax-invariant, dropped.
    float* out = (float*)d_out;
    char* ws = (char*)d_ws;

    const float c2 = 2.0f * LOG2E;

    proj_mfma<<<dim3(32, 4, 2), 256, 0, stream>>>(query, key, wq, wk, bq, bk, ws, c2);
    score_kernel<<<dim3(8, 8, Bb), 256, 0, stream>>>(wv, ws);
    av_mfma<<<dim3(8, 8, Bb), 256, 0, stream>>>(value, ws, out);
}